// Round 18
// baseline (398.143 us; speedup 1.0000x reference)
//
#include <hip/hip_runtime.h>
#include <hip/hip_bf16.h>

#define N_NODES 40000
#define N_EDGES 640000
#define HID 128
#define NB 64
#define F_IN 16
#define BN_EPS 1e-5f
#define NT_ROWS (N_NODES / 16)             // 2500 row-tiles
#define POOL_ROWS 40
#define POOL_NBLK (N_NODES / POOL_ROWS)    // 1000
#define CB 157                             // coarse buckets (dst>>8)
#define P1B 157                            // partition blocks (4096 edges ea)
#define BCAP 4480                          // fixed bucket capacity (4096+6sig)

typedef unsigned short u16;
typedef unsigned int u32;
typedef unsigned long long u64;
typedef __attribute__((ext_vector_type(8))) __bf16 bf16x8;
typedef __attribute__((ext_vector_type(8))) unsigned short u16x8;
typedef __attribute__((ext_vector_type(4))) float f32x4;

__device__ __forceinline__ float bf2f(u16 u) {
  u32 v = ((u32)u) << 16;
  return __builtin_bit_cast(float, v);
}
__device__ __forceinline__ u16 f2bf(float f) {
  u32 v = __builtin_bit_cast(u32, f);
  u32 r = 0x7FFFu + ((v >> 16) & 1u);  // round-to-nearest-even
  return (u16)((v + r) >> 16);
}
// packed edge-attr pair in high32: a0 in high 16 bits, a1 in low 16 bits
__device__ __forceinline__ float pk_hi(u32 p) {
  return __builtin_bit_cast(float, p & 0xFFFF0000u);
}
__device__ __forceinline__ float pk_lo(u32 p) {
  return __builtin_bit_cast(float, p << 16);
}

// ---------------------------------------------------------------------------
// W convert+transpose (5 weights, contiguous wt) + init work in block 0:
// bucket cursors bcur[b]=b*BCAP, zero stats (3x256) and pooled (64x128).
// Launched FIRST; stream order guarantees bcur ready before partition1.
// ---------------------------------------------------------------------------
__global__ __launch_bounds__(128) void wconv5_init(
    const float* __restrict__ W0, const float* __restrict__ W1,
    const float* __restrict__ W2, const float* __restrict__ W3,
    const float* __restrict__ W4, u16* __restrict__ wt_base,
    int* __restrict__ bcur, float* __restrict__ stat,
    float* __restrict__ pooled) {
  int which = blockIdx.x >> 7;
  int k = blockIdx.x & 127;
  int n = threadIdx.x;
  if (blockIdx.x == 0) {
    for (int i = n; i < CB; i += 128) bcur[i] = i * BCAP;
    for (int i = n; i < 768; i += 128) stat[i] = 0.f;
    for (int i = n; i < NB * HID; i += 128) pooled[i] = 0.f;
  }
  const float* W = (which == 0)   ? W0
                   : (which == 1) ? W1
                   : (which == 2) ? W2
                   : (which == 3) ? W3
                                  : W4;
  wt_base[(size_t)which * HID * HID + n * HID + k] = f2bf(W[k * HID + n]);
}

// ---------------------------------------------------------------------------
// P1: partition edges into fixed-capacity coarse buckets (dst>>8).
// rec: low32 = src | (dstLocal<<16); high32 = bf16(a0)<<16 | bf16(a1)
// ---------------------------------------------------------------------------
__global__ __launch_bounds__(256) void partition1(const int* __restrict__ ei,
                                                  const float* __restrict__ ea,
                                                  int* __restrict__ bcur,
                                                  u64* __restrict__ elc) {
  __shared__ int h[CB], base[CB];
  for (int t = threadIdx.x; t < CB; t += 256) h[t] = 0;
  __syncthreads();
  int eb = blockIdx.x * 4096;
#pragma unroll
  for (int k = 0; k < 16; k++) {
    int e = eb + k * 256 + threadIdx.x;
    if (e < N_EDGES) atomicAdd(&h[ei[N_EDGES + e] >> 8], 1);
  }
  __syncthreads();
  for (int t = threadIdx.x; t < CB; t += 256) {
    if (h[t]) base[t] = atomicAdd(&bcur[t], h[t]);
    h[t] = 0;  // reuse as running counter
  }
  __syncthreads();
#pragma unroll
  for (int k = 0; k < 16; k++) {
    int e = eb + k * 256 + threadIdx.x;
    if (e < N_EDGES) {
      int d = ei[N_EDGES + e];
      int b = d >> 8;
      int r = atomicAdd(&h[b], 1);
      float2 a = *(const float2*)(ea + 2 * e);
      u32 hi = ((u32)f2bf(a.x) << 16) | f2bf(a.y);
      u32 lo = (u32)ei[e] | ((u32)(d & 255) << 16);
      elc[base[b] + r] = ((u64)hi << 32) | lo;
    }
  }
}

// ---------------------------------------------------------------------------
// P2: per-bucket counting sort by dstLocal -> compacted dst-sorted elpk + offs
// Computes its own exclusive bucket base d0 by scanning bcur in LDS.
// ---------------------------------------------------------------------------
__global__ __launch_bounds__(256) void partition2(const u64* __restrict__ elc,
                                                  const int* __restrict__ bcur,
                                                  uint2* __restrict__ elpk,
                                                  int* __restrict__ offs) {
  __shared__ int h[256], ex[256];
  int b = blockIdx.x;
  int tid = threadIdx.x;
  int cnt = (tid < CB) ? (bcur[tid] - tid * BCAP) : 0;
  ex[tid] = cnt;
  __syncthreads();
#pragma unroll
  for (int off = 1; off < 256; off <<= 1) {
    int u = (tid >= off) ? ex[tid - off] : 0;
    __syncthreads();
    ex[tid] += u;
    __syncthreads();
  }
  int d0 = (b == 0) ? 0 : ex[b - 1];
  int s0 = b * BCAP, s1 = bcur[b];
  h[tid] = 0;
  __syncthreads();
  for (int j = s0 + tid; j < s1; j += 256) {
    u32 lo = (u32)elc[j];
    atomicAdd(&h[(lo >> 16) & 255], 1);
  }
  __syncthreads();
  ex[tid] = h[tid];
  __syncthreads();
#pragma unroll
  for (int off = 1; off < 256; off <<= 1) {
    int u = (tid >= off) ? ex[tid - off] : 0;
    __syncthreads();
    ex[tid] += u;
    __syncthreads();
  }
  int excl = ex[tid] - h[tid];
  int node = b * 256 + tid;
  if (node < N_NODES) offs[node] = d0 + excl;
  if (b == 0 && tid == 0) offs[N_NODES] = N_EDGES;
  h[tid] = d0 + excl;  // cursor
  __syncthreads();
  for (int j = s0 + tid; j < s1; j += 256) {
    u64 rec = elc[j];
    int dl = ((u32)rec >> 16) & 255;
    int pos = atomicAdd(&h[dl], 1);
    uint2 o;
    o.x = (u32)rec;
    o.y = (u32)(rec >> 32);
    elpk[pos] = o;
  }
}

// ---------------------------------------------------------------------------
// Aggregation d=128, bf16 in/out: out[i,:]=x[i,:]+sum_j relu(x[src_j]+ea@We+be)
// One wave per node, lane owns 2 features. 8-deep batch pipeline with
// branchless predicated tail (depth-8 = measured MLP sweet spot).
// Near random-gather HBM floor (~61MB FETCH @ ~2TB/s effective).
// ---------------------------------------------------------------------------
__global__ __launch_bounds__(64) void aggregate128_bf16(
    const u16* __restrict__ xb, const int* __restrict__ offs,
    const uint2* __restrict__ elpk, const float* __restrict__ We,
    const float* __restrict__ be, u16* __restrict__ out) {
  int i = blockIdx.x;
  int c = threadIdx.x * 2;
  float2 we0 = *(const float2*)(We + c);
  float2 we1 = *(const float2*)(We + HID + c);
  float2 bec = *(const float2*)(be + c);
  ushort2 xs = *(const ushort2*)(xb + (size_t)i * HID + c);
  float acc0 = bf2f(xs.x), acc1 = bf2f(xs.y);
  int s0 = offs[i], s1 = offs[i + 1];
  int n = s1 - s0;

#define EDGEM(rr, uu, mm)                                                    \
  {                                                                          \
    float a0 = pk_hi((rr).y), a1 = pk_lo((rr).y);                            \
    acc0 += (mm) * fmaxf(bf2f((uu).x) + a0 * we0.x + a1 * we1.x + bec.x,     \
                         0.f);                                               \
    acc1 += (mm) * fmaxf(bf2f((uu).y) + a0 * we0.y + a1 * we1.y + bec.y,     \
                         0.f);                                               \
  }
#define GATHER(rr) *(const ushort2*)(xb + (size_t)((rr).x & 0xFFFFu) * HID + c)

  if (n > 0) {
    int nb = (n + 7) >> 3;
    uint2 r[8];
    ushort2 u[8];
    float m[8];
#pragma unroll
    for (int k = 0; k < 8; k++) {
      int j = s0 + k;
      int jc = j < s1 ? j : s1 - 1;
      r[k] = elpk[jc];
      m[k] = j < s1 ? 1.f : 0.f;
      u[k] = GATHER(r[k]);
    }
    for (int b = 1; b < nb; b++) {
      int jb = s0 + b * 8;
      uint2 rn[8];
      ushort2 un[8];
      float mn[8];
#pragma unroll
      for (int k = 0; k < 8; k++) {
        int j = jb + k;
        int jc = j < s1 ? j : s1 - 1;
        rn[k] = elpk[jc];
        mn[k] = j < s1 ? 1.f : 0.f;
        un[k] = GATHER(rn[k]);
      }
#pragma unroll
      for (int k = 0; k < 8; k++) EDGEM(r[k], u[k], m[k]);
#pragma unroll
      for (int k = 0; k < 8; k++) {
        r[k] = rn[k];
        u[k] = un[k];
        m[k] = mn[k];
      }
    }
#pragma unroll
    for (int k = 0; k < 8; k++) EDGEM(r[k], u[k], m[k]);
  }
#undef GATHER
#undef EDGEM

  ushort2 o;
  o.x = f2bf(acc0);
  o.y = f2bf(acc1);
  *(ushort2*)(out + (size_t)i * HID + c) = o;
}

// ---------------------------------------------------------------------------
// FUSED layer-0 front-end: EDGE-PARALLEL aggregate d=16 + K=16 f32 GEMM.
// Block = 32 nodes, 256 threads. Phase 1: the block's 32 nodes own a
// contiguous slice of dst-sorted elpk (~512 edges); threads grid-stride it
// (coalesced rec reads, 4 independent float4 x-row loads each), accumulate
// relu(msg) into LDS Al[node][f] via ds_add_f32. Al stride 17 breaks the
// node*16 bank degeneracy. No per-node serial chains, no degree imbalance.
// Phase 2: 32-row K=16 GEMM from LDS (out bf16 + BN stats).
// ---------------------------------------------------------------------------
__global__ __launch_bounds__(256) void agg_gemm16(
    const float* __restrict__ x, const int* __restrict__ offs,
    const uint2* __restrict__ elpk, const float* __restrict__ We,
    const float* __restrict__ be, const float* __restrict__ W,
    const float* __restrict__ bias, u16* __restrict__ outb,
    float* __restrict__ stat) {
  constexpr int KT = 16;
  __shared__ float Wl[KT][HID];
  __shared__ float Al[32][17];
  __shared__ float red[8][2][HID];
  __shared__ float wel[2][KT], bel[KT];

  int tid = threadIdx.x;
  int row0 = blockIdx.x * 32;

  // stage W tile
  for (int i = tid; i < KT * (HID / 4); i += 256) {
    int k = i >> 5;
    int cc = (i & 31) << 2;
    *(float4*)&Wl[k][cc] = *(const float4*)(W + k * HID + cc);
  }
  if (tid < KT) {
    wel[0][tid] = We[tid];
    wel[1][tid] = We[KT + tid];
    bel[tid] = be[tid];
  }
  // init Al with self term x[i]
  for (int i = tid; i < 32 * KT; i += 256) {
    int nd = i >> 4, f = i & 15;
    Al[nd][f] = x[(row0 + nd) * F_IN + f];
  }
  __syncthreads();

  // phase 1: edge-parallel accumulate
  {
    int e0 = offs[row0];
    int e1 = offs[row0 + 32];
    int rbase = row0 & 255;  // 32-node block never straddles a 256-bucket
    for (int e = e0 + tid; e < e1; e += 256) {
      uint2 r = elpk[e];
      int src = r.x & 0xFFFF;
      int nd = ((r.x >> 16) & 255) - rbase;
      float a0 = pk_hi(r.y), a1 = pk_lo(r.y);
      float4 x0 = *(const float4*)(x + src * F_IN);
      float4 x1 = *(const float4*)(x + src * F_IN + 4);
      float4 x2 = *(const float4*)(x + src * F_IN + 8);
      float4 x3 = *(const float4*)(x + src * F_IN + 12);
      float xr[16] = {x0.x, x0.y, x0.z, x0.w, x1.x, x1.y, x1.z, x1.w,
                      x2.x, x2.y, x2.z, x2.w, x3.x, x3.y, x3.z, x3.w};
#pragma unroll
      for (int f = 0; f < 16; f++) {
        float v = fmaxf(xr[f] + a0 * wel[0][f] + a1 * wel[1][f] + bel[f], 0.f);
        atomicAdd(&Al[nd][f], v);
      }
    }
  }
  __syncthreads();

  // phase 2: K=16 GEMM from LDS
  int cg = tid & 31;
  int rg = tid >> 5;
  int c = cg << 2;

  float4 acc[4];
#pragma unroll
  for (int i = 0; i < 4; i++) acc[i] = make_float4(0.f, 0.f, 0.f, 0.f);
#pragma unroll
  for (int k = 0; k < KT; k++) {
    float4 w4 = *(float4*)&Wl[k][c];
#pragma unroll
    for (int i = 0; i < 4; i++) {
      float a = Al[rg * 4 + i][k];
      acc[i].x += a * w4.x;
      acc[i].y += a * w4.y;
      acc[i].z += a * w4.z;
      acc[i].w += a * w4.w;
    }
  }

  float4 bv = *(const float4*)(bias + c);
  float4 sm = make_float4(0.f, 0.f, 0.f, 0.f);
  float4 qm = make_float4(0.f, 0.f, 0.f, 0.f);
#pragma unroll
  for (int i = 0; i < 4; i++) {
    acc[i].x += bv.x; acc[i].y += bv.y; acc[i].z += bv.z; acc[i].w += bv.w;
    sm.x += acc[i].x; sm.y += acc[i].y; sm.z += acc[i].z; sm.w += acc[i].w;
    qm.x += acc[i].x * acc[i].x; qm.y += acc[i].y * acc[i].y;
    qm.z += acc[i].z * acc[i].z; qm.w += acc[i].w * acc[i].w;
    ushort4 o16;
    o16.x = f2bf(acc[i].x); o16.y = f2bf(acc[i].y);
    o16.z = f2bf(acc[i].z); o16.w = f2bf(acc[i].w);
    *(ushort4*)(outb + (size_t)(row0 + rg * 4 + i) * HID + c) = o16;
  }
  *(float4*)&red[rg][0][c] = sm;
  *(float4*)&red[rg][1][c] = qm;
  __syncthreads();
  if (tid < HID) {
    float sv = 0.f, qv = 0.f;
#pragma unroll
    for (int r = 0; r < 8; r++) {
      sv += red[r][0][tid];
      qv += red[r][1][tid];
    }
    atomicAdd(stat + tid, sv);
    atomicAdd(stat + HID + tid, qv);
  }
}

// ---------------------------------------------------------------------------
// MFMA bf16 GEMM: out[N,128] = A[N,128] @ W[128,128] + bias    (out bf16)
//   PRO  : BN scale/shift computed IN-BLOCK from stat_in/g/bt into LDS
//   STATS: per-column sum/sumsq of (acc+bias) accumulated -> stat_out[256]
//   RELU : relu on output
// Grid 313 (1252 waves, 2 row-tiles each) = measured optimum: B-panel
// staging (8KB Wt/wave) amortized over 2 tiles; 625/1-tile regressed.
// ---------------------------------------------------------------------------
template <bool PRO, bool STATS, bool RELU>
__global__ __launch_bounds__(256, 2) void gemm_mfma(
    const u16* __restrict__ Ab, const u16* __restrict__ Wt,
    const float* __restrict__ bias, const float* __restrict__ stat_in,
    const float* __restrict__ gg, const float* __restrict__ btp,
    u16* __restrict__ outb, float* __restrict__ stat_out) {
  __shared__ float sc[HID], sh[HID];
  int tid = threadIdx.x;
  int lane = tid & 63;
  int wid = tid >> 6;
  int l15 = lane & 15;
  int quad = lane >> 4;
  int gwave = blockIdx.x * 4 + wid;
  int nwaves = gridDim.x * 4;

  if (PRO) {
    if (tid < HID) {
      float mu = stat_in[tid] * (1.f / N_NODES);
      float var = stat_in[HID + tid] * (1.f / N_NODES) - mu * mu;
      float s = gg[tid] * rsqrtf(var + BN_EPS);
      sc[tid] = s;
      sh[tid] = btp[tid] - mu * s;
    }
    __syncthreads();
  }

  bf16x8 bfr[8][4];
#pragma unroll
  for (int ct = 0; ct < 8; ct++)
#pragma unroll
    for (int ks = 0; ks < 4; ks++)
      bfr[ct][ks] = __builtin_bit_cast(
          bf16x8, *(const u16x8*)(Wt + (size_t)(ct * 16 + l15) * HID +
                                  ks * 32 + quad * 8));

  float bv[8];
#pragma unroll
  for (int ct = 0; ct < 8; ct++) bv[ct] = bias[ct * 16 + l15];

  float s[8], q[8];
  if (STATS) {
#pragma unroll
    for (int ct = 0; ct < 8; ct++) {
      s[ct] = 0.f;
      q[ct] = 0.f;
    }
  }

  for (int t = gwave; t < NT_ROWS; t += nwaves) {
    int r0 = t * 16;
    const u16* arow = Ab + (size_t)(r0 + l15) * HID + quad * 8;
    bf16x8 af[4];
#pragma unroll
    for (int ks = 0; ks < 4; ks++) {
      u16x8 raw = *(const u16x8*)(arow + ks * 32);
      if (PRO) {
        u16x8 pr;
#pragma unroll
        for (int j = 0; j < 8; j++) {
          int k = ks * 32 + quad * 8 + j;
          float v = bf2f(raw[j]);
          v = fmaxf(v * sc[k] + sh[k], 0.f);
          pr[j] = f2bf(v);
        }
        raw = pr;
      }
      af[ks] = __builtin_bit_cast(bf16x8, raw);
    }

    f32x4 acc[8];
#pragma unroll
    for (int ct = 0; ct < 8; ct++) acc[ct] = (f32x4){0.f, 0.f, 0.f, 0.f};
#pragma unroll
    for (int ks = 0; ks < 4; ks++)
#pragma unroll
      for (int ct = 0; ct < 8; ct++)
        acc[ct] = __builtin_amdgcn_mfma_f32_16x16x32_bf16(af[ks], bfr[ct][ks],
                                                          acc[ct], 0, 0, 0);

#pragma unroll
    for (int ct = 0; ct < 8; ct++) {
      u16* op = outb + (size_t)(r0 + quad * 4) * HID + ct * 16 + l15;
#pragma unroll
      for (int r = 0; r < 4; r++) {
        float h = acc[ct][r] + bv[ct];
        if (STATS) {
          s[ct] += h;
          q[ct] += h * h;
        }
        if (RELU) h = fmaxf(h, 0.f);
        op[(size_t)r * HID] = f2bf(h);
      }
    }
  }

  if (STATS) {
    __shared__ float sred[4][256];
#pragma unroll
    for (int ct = 0; ct < 8; ct++) {
      float sv = s[ct], qv = q[ct];
      sv += __shfl_xor(sv, 16);
      sv += __shfl_xor(sv, 32);
      qv += __shfl_xor(qv, 16);
      qv += __shfl_xor(qv, 32);
      if (quad == 0) {
        sred[wid][ct * 16 + l15] = sv;
        sred[wid][128 + ct * 16 + l15] = qv;
      }
    }
    __syncthreads();
    float tot = sred[0][tid] + sred[1][tid] + sred[2][tid] + sred[3][tid];
    atomicAdd(stat_out + tid, tot);
  }
}

// ---------------------------------------------------------------------------
// Batch pooling over bf16 x (batch sorted): 1000 blocks x 1 wave, 40 rows
// each, lane owns 2 features (ushort2). Flush on segment change only.
// ---------------------------------------------------------------------------
__global__ __launch_bounds__(64) void pool_kernel(
    const u16* __restrict__ xb, const int* __restrict__ batch,
    float* __restrict__ pooled) {
  int c = threadIdx.x * 2;
  int r0 = blockIdx.x * POOL_ROWS;
  int r1 = r0 + POOL_ROWS;
  if (r1 > N_NODES) r1 = N_NODES;
  float a0 = 0.f, a1 = 0.f;
  int cur = batch[r0];
  for (int r = r0; r < r1; r++) {
    int b = batch[r];
    if (b != cur) {
      atomicAdd(pooled + cur * HID + c, a0);
      atomicAdd(pooled + cur * HID + c + 1, a1);
      a0 = 0.f;
      a1 = 0.f;
      cur = b;
    }
    ushort2 u = *(const ushort2*)(xb + (size_t)r * HID + c);
    a0 += bf2f(u.x);
    a1 += bf2f(u.y);
  }
  atomicAdd(pooled + cur * HID + c, a0);
  atomicAdd(pooled + cur * HID + c + 1, a1);
}

// ---------------------------------------------------------------------------
__global__ __launch_bounds__(128) void final_mlp(
    const float* __restrict__ pooled, const float* __restrict__ Wf1,
    const float* __restrict__ bf1, const float* __restrict__ Wf2,
    const float* __restrict__ bf2, float* __restrict__ out) {
  __shared__ float pr[HID];
  __shared__ float h[HID];
  int b = blockIdx.x, c = threadIdx.x;
  pr[c] = pooled[b * HID + c];
  __syncthreads();
  float acc = bf1[c];
  for (int k = 0; k < HID; k++) acc += pr[k] * Wf1[k * HID + c];
  h[c] = fmaxf(acc, 0.f);
  __syncthreads();
  if (c < 8) {
    float o = bf2[c];
    for (int k = 0; k < HID; k++) o += h[k] * Wf2[k * 8 + c];
    out[b * 8 + c] = o;
  }
}

// ---------------------------------------------------------------------------
extern "C" void kernel_launch(void* const* d_in, const int* in_sizes, int n_in,
                              void* d_out, int out_size, void* d_ws,
                              size_t ws_size, hipStream_t stream) {
  const float* x_in = (const float*)d_in[0];
  const int* ei = (const int*)d_in[1];
  const float* ea = (const float*)d_in[2];
  const int* batch = (const int*)d_in[3];
  const float* We[3], *be[3], *W1[3], *b1[3], *g[3], *bt[3], *W2[3], *b2[3];
  for (int l = 0; l < 3; l++) {
    int i0 = 5 + 8 * l;
    We[l] = (const float*)d_in[i0 + 0];
    be[l] = (const float*)d_in[i0 + 1];
    W1[l] = (const float*)d_in[i0 + 2];
    b1[l] = (const float*)d_in[i0 + 3];
    g[l] = (const float*)d_in[i0 + 4];
    bt[l] = (const float*)d_in[i0 + 5];
    W2[l] = (const float*)d_in[i0 + 6];
    b2[l] = (const float*)d_in[i0 + 7];
  }
  const float* Wf1 = (const float*)d_in[29];
  const float* bf1 = (const float*)d_in[30];
  const float* Wf2 = (const float*)d_in[31];
  const float* bf2 = (const float*)d_in[32];
  float* out = (float*)d_out;

  const size_t NH = (size_t)N_NODES * HID;
  u16* xb = (u16*)d_ws;                  // [N,128] bf16 layer output
  u16* abuf = xb + NH;                   // [N,128] bf16 aggregation
  u16* hbuf = abuf + NH;                 // [N,128] bf16 hidden (pre-BN)
  float* stat0 = (float*)(hbuf + NH);    // 3 x [256]
  float* stat1 = stat0 + 256;
  float* stat2 = stat1 + 256;
  float* pooled = stat2 + 256;           // [64,128]
  u16* wt = (u16*)(pooled + NB * HID);   // 5 x [128,128] bf16 (contiguous)
  int* bcur = (int*)(wt + 5 * HID * HID);  // [160]
  int* offs = bcur + 160;                // [40002]
  u64* elc = (u64*)(offs + 40002);       // [CB*BCAP] bucketed records
  uint2* elpk = (uint2*)(elc + (size_t)CB * BCAP);  // [E] dst-sorted records
  float* stats[3] = {stat0, stat1, stat2};
  // wt order: [0]=W2t l0, [1]=W1t l1, [2]=W2t l1, [3]=W1t l2, [4]=W2t l2

  // ---------------- W transposes + init (one launch, runs first) ----------
  hipLaunchKernelGGL(wconv5_init, dim3(5 * HID), dim3(HID), 0, stream, W2[0],
                     W1[1], W2[1], W1[2], W2[2], wt, bcur, stat0, pooled);

  // ---------------- CSR build: fixed-capacity radix partition --------------
  hipLaunchKernelGGL(partition1, dim3(P1B), dim3(256), 0, stream, ei, ea, bcur,
                     elc);
  hipLaunchKernelGGL(partition2, dim3(CB), dim3(256), 0, stream, elc, bcur,
                     elpk, offs);

  const int GMB = 313;  // gemm_mfma grid: 1252 waves, 2 tiles/wave (optimum)
  const size_t WT = (size_t)HID * HID;

  // ---------------- Layer 0 (d = 16): fused aggregate + K=16 GEMM ----------
  hipLaunchKernelGGL(agg_gemm16, dim3(N_NODES / 32), dim3(256), 0, stream,
                     x_in, offs, elpk, We[0], be[0], W1[0], b1[0], hbuf,
                     stat0);
  hipLaunchKernelGGL((gemm_mfma<true, false, true>), dim3(GMB), dim3(256), 0,
                     stream, hbuf, wt, b2[0], stat0, g[0], bt[0], xb, nullptr);

  // ---------------- Layers 1, 2 (d = 128) ----------------
  for (int l = 1; l < 3; l++) {
    hipLaunchKernelGGL(aggregate128_bf16, dim3(N_NODES), dim3(64), 0, stream,
                       xb, offs, elpk, We[l], be[l], abuf);
    hipLaunchKernelGGL((gemm_mfma<false, true, false>), dim3(GMB), dim3(256),
                       0, stream, abuf, wt + (2 * l - 1) * WT, b1[l], nullptr,
                       nullptr, nullptr, hbuf, stats[l]);
    hipLaunchKernelGGL((gemm_mfma<true, false, true>), dim3(GMB), dim3(256), 0,
                       stream, hbuf, wt + (2 * l) * WT, b2[l], stats[l], g[l],
                       bt[l], xb, nullptr);
  }

  // ---------------- Pool + final MLP ----------------
  hipLaunchKernelGGL(pool_kernel, dim3(POOL_NBLK), dim3(64), 0, stream, xb,
                     batch, pooled);
  hipLaunchKernelGGL(final_mlp, dim3(NB), dim3(128), 0, stream, pooled, Wf1,
                     bf1, Wf2, bf2, out);
}

// Round 19
// 353.659 us; speedup vs baseline: 1.1258x; 1.1258x over previous
//
#include <hip/hip_runtime.h>
#include <hip/hip_bf16.h>

#define N_NODES 40000
#define N_EDGES 640000
#define HID 128
#define NB 64
#define F_IN 16
#define BN_EPS 1e-5f
#define NT_ROWS (N_NODES / 16)             // 2500 row-tiles
#define POOL_ROWS 40
#define POOL_NBLK (N_NODES / POOL_ROWS)    // 1000
#define CB 157                             // coarse buckets (dst>>8)
#define P1B 157                            // partition blocks (4096 edges ea)
#define BCAP 4480                          // fixed bucket capacity (4096+6sig)

typedef unsigned short u16;
typedef unsigned int u32;
typedef unsigned long long u64;
typedef __attribute__((ext_vector_type(8))) __bf16 bf16x8;
typedef __attribute__((ext_vector_type(8))) unsigned short u16x8;
typedef __attribute__((ext_vector_type(4))) float f32x4;

__device__ __forceinline__ float bf2f(u16 u) {
  u32 v = ((u32)u) << 16;
  return __builtin_bit_cast(float, v);
}
__device__ __forceinline__ u16 f2bf(float f) {
  u32 v = __builtin_bit_cast(u32, f);
  u32 r = 0x7FFFu + ((v >> 16) & 1u);  // round-to-nearest-even
  return (u16)((v + r) >> 16);
}
// packed edge-attr pair in high32: a0 in high 16 bits, a1 in low 16 bits
__device__ __forceinline__ float pk_hi(u32 p) {
  return __builtin_bit_cast(float, p & 0xFFFF0000u);
}
__device__ __forceinline__ float pk_lo(u32 p) {
  return __builtin_bit_cast(float, p << 16);
}

// ---------------------------------------------------------------------------
// W convert+transpose (5 weights, contiguous wt) + init work in block 0:
// bucket cursors bcur[b]=b*BCAP, zero stats (3x256) and pooled (64x128).
// Launched FIRST; stream order guarantees bcur ready before partition1.
// ---------------------------------------------------------------------------
__global__ __launch_bounds__(128) void wconv5_init(
    const float* __restrict__ W0, const float* __restrict__ W1,
    const float* __restrict__ W2, const float* __restrict__ W3,
    const float* __restrict__ W4, u16* __restrict__ wt_base,
    int* __restrict__ bcur, float* __restrict__ stat,
    float* __restrict__ pooled) {
  int which = blockIdx.x >> 7;
  int k = blockIdx.x & 127;
  int n = threadIdx.x;
  if (blockIdx.x == 0) {
    for (int i = n; i < CB; i += 128) bcur[i] = i * BCAP;
    for (int i = n; i < 768; i += 128) stat[i] = 0.f;
    for (int i = n; i < NB * HID; i += 128) pooled[i] = 0.f;
  }
  const float* W = (which == 0)   ? W0
                   : (which == 1) ? W1
                   : (which == 2) ? W2
                   : (which == 3) ? W3
                                  : W4;
  wt_base[(size_t)which * HID * HID + n * HID + k] = f2bf(W[k * HID + n]);
}

// ---------------------------------------------------------------------------
// P1: partition edges into fixed-capacity coarse buckets (dst>>8).
// rec: low32 = src | (dstLocal<<16); high32 = bf16(a0)<<16 | bf16(a1)
// ---------------------------------------------------------------------------
__global__ __launch_bounds__(256) void partition1(const int* __restrict__ ei,
                                                  const float* __restrict__ ea,
                                                  int* __restrict__ bcur,
                                                  u64* __restrict__ elc) {
  __shared__ int h[CB], base[CB];
  for (int t = threadIdx.x; t < CB; t += 256) h[t] = 0;
  __syncthreads();
  int eb = blockIdx.x * 4096;
#pragma unroll
  for (int k = 0; k < 16; k++) {
    int e = eb + k * 256 + threadIdx.x;
    if (e < N_EDGES) atomicAdd(&h[ei[N_EDGES + e] >> 8], 1);
  }
  __syncthreads();
  for (int t = threadIdx.x; t < CB; t += 256) {
    if (h[t]) base[t] = atomicAdd(&bcur[t], h[t]);
    h[t] = 0;  // reuse as running counter
  }
  __syncthreads();
#pragma unroll
  for (int k = 0; k < 16; k++) {
    int e = eb + k * 256 + threadIdx.x;
    if (e < N_EDGES) {
      int d = ei[N_EDGES + e];
      int b = d >> 8;
      int r = atomicAdd(&h[b], 1);
      float2 a = *(const float2*)(ea + 2 * e);
      u32 hi = ((u32)f2bf(a.x) << 16) | f2bf(a.y);
      u32 lo = (u32)ei[e] | ((u32)(d & 255) << 16);
      elc[base[b] + r] = ((u64)hi << 32) | lo;
    }
  }
}

// ---------------------------------------------------------------------------
// P2: per-bucket counting sort by dstLocal -> compacted dst-sorted elpk + offs
// Computes its own exclusive bucket base d0 by scanning bcur in LDS.
// ---------------------------------------------------------------------------
__global__ __launch_bounds__(256) void partition2(const u64* __restrict__ elc,
                                                  const int* __restrict__ bcur,
                                                  uint2* __restrict__ elpk,
                                                  int* __restrict__ offs) {
  __shared__ int h[256], ex[256];
  int b = blockIdx.x;
  int tid = threadIdx.x;
  int cnt = (tid < CB) ? (bcur[tid] - tid * BCAP) : 0;
  ex[tid] = cnt;
  __syncthreads();
#pragma unroll
  for (int off = 1; off < 256; off <<= 1) {
    int u = (tid >= off) ? ex[tid - off] : 0;
    __syncthreads();
    ex[tid] += u;
    __syncthreads();
  }
  int d0 = (b == 0) ? 0 : ex[b - 1];
  int s0 = b * BCAP, s1 = bcur[b];
  h[tid] = 0;
  __syncthreads();
  for (int j = s0 + tid; j < s1; j += 256) {
    u32 lo = (u32)elc[j];
    atomicAdd(&h[(lo >> 16) & 255], 1);
  }
  __syncthreads();
  ex[tid] = h[tid];
  __syncthreads();
#pragma unroll
  for (int off = 1; off < 256; off <<= 1) {
    int u = (tid >= off) ? ex[tid - off] : 0;
    __syncthreads();
    ex[tid] += u;
    __syncthreads();
  }
  int excl = ex[tid] - h[tid];
  int node = b * 256 + tid;
  if (node < N_NODES) offs[node] = d0 + excl;
  if (b == 0 && tid == 0) offs[N_NODES] = N_EDGES;
  h[tid] = d0 + excl;  // cursor
  __syncthreads();
  for (int j = s0 + tid; j < s1; j += 256) {
    u64 rec = elc[j];
    int dl = ((u32)rec >> 16) & 255;
    int pos = atomicAdd(&h[dl], 1);
    uint2 o;
    o.x = (u32)rec;
    o.y = (u32)(rec >> 32);
    elpk[pos] = o;
  }
}

// ---------------------------------------------------------------------------
// Aggregation d=128, bf16 in/out: out[i,:]=x[i,:]+sum_j relu(x[src_j]+ea@We+be)
// One wave per node, lane owns 2 features. 8-deep batch pipeline with
// branchless predicated tail (depth-8 = measured MLP sweet spot).
// ---------------------------------------------------------------------------
__global__ __launch_bounds__(64) void aggregate128_bf16(
    const u16* __restrict__ xb, const int* __restrict__ offs,
    const uint2* __restrict__ elpk, const float* __restrict__ We,
    const float* __restrict__ be, u16* __restrict__ out) {
  int i = blockIdx.x;
  int c = threadIdx.x * 2;
  float2 we0 = *(const float2*)(We + c);
  float2 we1 = *(const float2*)(We + HID + c);
  float2 bec = *(const float2*)(be + c);
  ushort2 xs = *(const ushort2*)(xb + (size_t)i * HID + c);
  float acc0 = bf2f(xs.x), acc1 = bf2f(xs.y);
  int s0 = offs[i], s1 = offs[i + 1];
  int n = s1 - s0;

#define EDGEM(rr, uu, mm)                                                    \
  {                                                                          \
    float a0 = pk_hi((rr).y), a1 = pk_lo((rr).y);                            \
    acc0 += (mm) * fmaxf(bf2f((uu).x) + a0 * we0.x + a1 * we1.x + bec.x,     \
                         0.f);                                               \
    acc1 += (mm) * fmaxf(bf2f((uu).y) + a0 * we0.y + a1 * we1.y + bec.y,     \
                         0.f);                                               \
  }
#define GATHER(rr) *(const ushort2*)(xb + (size_t)((rr).x & 0xFFFFu) * HID + c)

  if (n > 0) {
    int nb = (n + 7) >> 3;
    uint2 r[8];
    ushort2 u[8];
    float m[8];
#pragma unroll
    for (int k = 0; k < 8; k++) {
      int j = s0 + k;
      int jc = j < s1 ? j : s1 - 1;
      r[k] = elpk[jc];
      m[k] = j < s1 ? 1.f : 0.f;
      u[k] = GATHER(r[k]);
    }
    for (int b = 1; b < nb; b++) {
      int jb = s0 + b * 8;
      uint2 rn[8];
      ushort2 un[8];
      float mn[8];
#pragma unroll
      for (int k = 0; k < 8; k++) {
        int j = jb + k;
        int jc = j < s1 ? j : s1 - 1;
        rn[k] = elpk[jc];
        mn[k] = j < s1 ? 1.f : 0.f;
        un[k] = GATHER(rn[k]);
      }
#pragma unroll
      for (int k = 0; k < 8; k++) EDGEM(r[k], u[k], m[k]);
#pragma unroll
      for (int k = 0; k < 8; k++) {
        r[k] = rn[k];
        u[k] = un[k];
        m[k] = mn[k];
      }
    }
#pragma unroll
    for (int k = 0; k < 8; k++) EDGEM(r[k], u[k], m[k]);
  }
#undef GATHER
#undef EDGEM

  ushort2 o;
  o.x = f2bf(acc0);
  o.y = f2bf(acc1);
  *(ushort2*)(out + (size_t)i * HID + c) = o;
}

// ---------------------------------------------------------------------------
// FUSED layer-0 front-end: aggregate d=16 (into LDS) + K=16 f32 GEMM.
// Block = 32 nodes, 256 threads — measured optimum. Variants tested and
// rejected: 16-node/128-thr granule (74us), edge-parallel LDS atomics
// (87us — dst-sorted edges make same-address LDS atomic chains).
// Phase 1: 16 threads/node x 2 passes, depth-4 predicated pipeline -> Al.
// Phase 2: 32-row K=16 GEMM from LDS (out bf16 + BN stats).
// ---------------------------------------------------------------------------
__global__ __launch_bounds__(256) void agg_gemm16(
    const float* __restrict__ x, const int* __restrict__ offs,
    const uint2* __restrict__ elpk, const float* __restrict__ We,
    const float* __restrict__ be, const float* __restrict__ W,
    const float* __restrict__ bias, u16* __restrict__ outb,
    float* __restrict__ stat) {
  constexpr int KT = 16;
  __shared__ float Wl[KT][HID];
  __shared__ float Al[32][KT];
  __shared__ float red[8][2][HID];

  int tid = threadIdx.x;
  int row0 = blockIdx.x * 32;

  // stage W tile (independent of phase-1 writes)
  for (int i = tid; i < KT * (HID / 4); i += 256) {
    int k = i >> 5;
    int cc = (i & 31) << 2;
    *(float4*)&Wl[k][cc] = *(const float4*)(W + k * HID + cc);
  }

  // phase 1: aggregate 32 nodes (16 threads per node, 2 passes)
  {
    int c = tid & 15;
    float we0 = We[c], we1 = We[F_IN + c], bec = be[c];
#pragma unroll
    for (int half = 0; half < 2; half++) {
      int node = half * 16 + (tid >> 4);
      int i = row0 + node;
      float acc = x[i * F_IN + c];
      int s0 = offs[i], s1 = offs[i + 1];
      int n = s1 - s0;
      if (n > 0) {
        int nb = (n + 3) >> 2;
        uint2 r[4];
        float xv[4], m[4];
#pragma unroll
        for (int k = 0; k < 4; k++) {
          int j = s0 + k;
          int jc = j < s1 ? j : s1 - 1;
          r[k] = elpk[jc];
          m[k] = j < s1 ? 1.f : 0.f;
          xv[k] = x[(r[k].x & 0xFFFFu) * F_IN + c];
        }
        for (int b = 1; b < nb; b++) {
          int jb = s0 + b * 4;
          uint2 rn[4];
          float xn[4], mn[4];
#pragma unroll
          for (int k = 0; k < 4; k++) {
            int j = jb + k;
            int jc = j < s1 ? j : s1 - 1;
            rn[k] = elpk[jc];
            mn[k] = j < s1 ? 1.f : 0.f;
            xn[k] = x[(rn[k].x & 0xFFFFu) * F_IN + c];
          }
#pragma unroll
          for (int k = 0; k < 4; k++)
            acc += m[k] * fmaxf(xv[k] + pk_hi(r[k].y) * we0 +
                                pk_lo(r[k].y) * we1 + bec, 0.f);
#pragma unroll
          for (int k = 0; k < 4; k++) {
            r[k] = rn[k];
            xv[k] = xn[k];
            m[k] = mn[k];
          }
        }
#pragma unroll
        for (int k = 0; k < 4; k++)
          acc += m[k] * fmaxf(xv[k] + pk_hi(r[k].y) * we0 +
                              pk_lo(r[k].y) * we1 + bec, 0.f);
      }
      Al[node][c] = acc;
    }
  }
  __syncthreads();

  // phase 2: K=16 GEMM from LDS
  int cg = tid & 31;
  int rg = tid >> 5;
  int c = cg << 2;

  float4 acc[4];
#pragma unroll
  for (int i = 0; i < 4; i++) acc[i] = make_float4(0.f, 0.f, 0.f, 0.f);
#pragma unroll
  for (int k = 0; k < KT; k++) {
    float4 w4 = *(float4*)&Wl[k][c];
#pragma unroll
    for (int i = 0; i < 4; i++) {
      float a = Al[rg * 4 + i][k];
      acc[i].x += a * w4.x;
      acc[i].y += a * w4.y;
      acc[i].z += a * w4.z;
      acc[i].w += a * w4.w;
    }
  }

  float4 bv = *(const float4*)(bias + c);
  float4 sm = make_float4(0.f, 0.f, 0.f, 0.f);
  float4 qm = make_float4(0.f, 0.f, 0.f, 0.f);
#pragma unroll
  for (int i = 0; i < 4; i++) {
    acc[i].x += bv.x; acc[i].y += bv.y; acc[i].z += bv.z; acc[i].w += bv.w;
    sm.x += acc[i].x; sm.y += acc[i].y; sm.z += acc[i].z; sm.w += acc[i].w;
    qm.x += acc[i].x * acc[i].x; qm.y += acc[i].y * acc[i].y;
    qm.z += acc[i].z * acc[i].z; qm.w += acc[i].w * acc[i].w;
    ushort4 o16;
    o16.x = f2bf(acc[i].x); o16.y = f2bf(acc[i].y);
    o16.z = f2bf(acc[i].z); o16.w = f2bf(acc[i].w);
    *(ushort4*)(outb + (size_t)(row0 + rg * 4 + i) * HID + c) = o16;
  }
  *(float4*)&red[rg][0][c] = sm;
  *(float4*)&red[rg][1][c] = qm;
  __syncthreads();
  if (tid < HID) {
    float sv = 0.f, qv = 0.f;
#pragma unroll
    for (int r = 0; r < 8; r++) {
      sv += red[r][0][tid];
      qv += red[r][1][tid];
    }
    atomicAdd(stat + tid, sv);
    atomicAdd(stat + HID + tid, qv);
  }
}

// ---------------------------------------------------------------------------
// MFMA bf16 GEMM: out[N,128] = A[N,128] @ W[128,128] + bias    (out bf16)
//   PRO  : BN scale/shift computed IN-BLOCK from stat_in/g/bt into LDS
//   STATS: per-column sum/sumsq of (acc+bias) accumulated -> stat_out[256]
//   RELU : relu on output
// Grid 313 (1252 waves, 2 row-tiles each) = measured optimum: B-panel
// staging (8KB Wt/wave) amortized over 2 tiles; 625/1-tile regressed.
// ---------------------------------------------------------------------------
template <bool PRO, bool STATS, bool RELU>
__global__ __launch_bounds__(256, 2) void gemm_mfma(
    const u16* __restrict__ Ab, const u16* __restrict__ Wt,
    const float* __restrict__ bias, const float* __restrict__ stat_in,
    const float* __restrict__ gg, const float* __restrict__ btp,
    u16* __restrict__ outb, float* __restrict__ stat_out) {
  __shared__ float sc[HID], sh[HID];
  int tid = threadIdx.x;
  int lane = tid & 63;
  int wid = tid >> 6;
  int l15 = lane & 15;
  int quad = lane >> 4;
  int gwave = blockIdx.x * 4 + wid;
  int nwaves = gridDim.x * 4;

  if (PRO) {
    if (tid < HID) {
      float mu = stat_in[tid] * (1.f / N_NODES);
      float var = stat_in[HID + tid] * (1.f / N_NODES) - mu * mu;
      float s = gg[tid] * rsqrtf(var + BN_EPS);
      sc[tid] = s;
      sh[tid] = btp[tid] - mu * s;
    }
    __syncthreads();
  }

  bf16x8 bfr[8][4];
#pragma unroll
  for (int ct = 0; ct < 8; ct++)
#pragma unroll
    for (int ks = 0; ks < 4; ks++)
      bfr[ct][ks] = __builtin_bit_cast(
          bf16x8, *(const u16x8*)(Wt + (size_t)(ct * 16 + l15) * HID +
                                  ks * 32 + quad * 8));

  float bv[8];
#pragma unroll
  for (int ct = 0; ct < 8; ct++) bv[ct] = bias[ct * 16 + l15];

  float s[8], q[8];
  if (STATS) {
#pragma unroll
    for (int ct = 0; ct < 8; ct++) {
      s[ct] = 0.f;
      q[ct] = 0.f;
    }
  }

  for (int t = gwave; t < NT_ROWS; t += nwaves) {
    int r0 = t * 16;
    const u16* arow = Ab + (size_t)(r0 + l15) * HID + quad * 8;
    bf16x8 af[4];
#pragma unroll
    for (int ks = 0; ks < 4; ks++) {
      u16x8 raw = *(const u16x8*)(arow + ks * 32);
      if (PRO) {
        u16x8 pr;
#pragma unroll
        for (int j = 0; j < 8; j++) {
          int k = ks * 32 + quad * 8 + j;
          float v = bf2f(raw[j]);
          v = fmaxf(v * sc[k] + sh[k], 0.f);
          pr[j] = f2bf(v);
        }
        raw = pr;
      }
      af[ks] = __builtin_bit_cast(bf16x8, raw);
    }

    f32x4 acc[8];
#pragma unroll
    for (int ct = 0; ct < 8; ct++) acc[ct] = (f32x4){0.f, 0.f, 0.f, 0.f};
#pragma unroll
    for (int ks = 0; ks < 4; ks++)
#pragma unroll
      for (int ct = 0; ct < 8; ct++)
        acc[ct] = __builtin_amdgcn_mfma_f32_16x16x32_bf16(af[ks], bfr[ct][ks],
                                                          acc[ct], 0, 0, 0);

#pragma unroll
    for (int ct = 0; ct < 8; ct++) {
      u16* op = outb + (size_t)(r0 + quad * 4) * HID + ct * 16 + l15;
#pragma unroll
      for (int r = 0; r < 4; r++) {
        float h = acc[ct][r] + bv[ct];
        if (STATS) {
          s[ct] += h;
          q[ct] += h * h;
        }
        if (RELU) h = fmaxf(h, 0.f);
        op[(size_t)r * HID] = f2bf(h);
      }
    }
  }

  if (STATS) {
    __shared__ float sred[4][256];
#pragma unroll
    for (int ct = 0; ct < 8; ct++) {
      float sv = s[ct], qv = q[ct];
      sv += __shfl_xor(sv, 16);
      sv += __shfl_xor(sv, 32);
      qv += __shfl_xor(qv, 16);
      qv += __shfl_xor(qv, 32);
      if (quad == 0) {
        sred[wid][ct * 16 + l15] = sv;
        sred[wid][128 + ct * 16 + l15] = qv;
      }
    }
    __syncthreads();
    float tot = sred[0][tid] + sred[1][tid] + sred[2][tid] + sred[3][tid];
    atomicAdd(stat_out + tid, tot);
  }
}

// ---------------------------------------------------------------------------
// Batch pooling over bf16 x (batch sorted): 1000 blocks x 1 wave, 40 rows
// each, lane owns 2 features (ushort2). Flush on segment change only.
// ---------------------------------------------------------------------------
__global__ __launch_bounds__(64) void pool_kernel(
    const u16* __restrict__ xb, const int* __restrict__ batch,
    float* __restrict__ pooled) {
  int c = threadIdx.x * 2;
  int r0 = blockIdx.x * POOL_ROWS;
  int r1 = r0 + POOL_ROWS;
  if (r1 > N_NODES) r1 = N_NODES;
  float a0 = 0.f, a1 = 0.f;
  int cur = batch[r0];
  for (int r = r0; r < r1; r++) {
    int b = batch[r];
    if (b != cur) {
      atomicAdd(pooled + cur * HID + c, a0);
      atomicAdd(pooled + cur * HID + c + 1, a1);
      a0 = 0.f;
      a1 = 0.f;
      cur = b;
    }
    ushort2 u = *(const ushort2*)(xb + (size_t)r * HID + c);
    a0 += bf2f(u.x);
    a1 += bf2f(u.y);
  }
  atomicAdd(pooled + cur * HID + c, a0);
  atomicAdd(pooled + cur * HID + c + 1, a1);
}

// ---------------------------------------------------------------------------
__global__ __launch_bounds__(128) void final_mlp(
    const float* __restrict__ pooled, const float* __restrict__ Wf1,
    const float* __restrict__ bf1, const float* __restrict__ Wf2,
    const float* __restrict__ bf2, float* __restrict__ out) {
  __shared__ float pr[HID];
  __shared__ float h[HID];
  int b = blockIdx.x, c = threadIdx.x;
  pr[c] = pooled[b * HID + c];
  __syncthreads();
  float acc = bf1[c];
  for (int k = 0; k < HID; k++) acc += pr[k] * Wf1[k * HID + c];
  h[c] = fmaxf(acc, 0.f);
  __syncthreads();
  if (c < 8) {
    float o = bf2[c];
    for (int k = 0; k < HID; k++) o += h[k] * Wf2[k * 8 + c];
    out[b * 8 + c] = o;
  }
}

// ---------------------------------------------------------------------------
extern "C" void kernel_launch(void* const* d_in, const int* in_sizes, int n_in,
                              void* d_out, int out_size, void* d_ws,
                              size_t ws_size, hipStream_t stream) {
  const float* x_in = (const float*)d_in[0];
  const int* ei = (const int*)d_in[1];
  const float* ea = (const float*)d_in[2];
  const int* batch = (const int*)d_in[3];
  const float* We[3], *be[3], *W1[3], *b1[3], *g[3], *bt[3], *W2[3], *b2[3];
  for (int l = 0; l < 3; l++) {
    int i0 = 5 + 8 * l;
    We[l] = (const float*)d_in[i0 + 0];
    be[l] = (const float*)d_in[i0 + 1];
    W1[l] = (const float*)d_in[i0 + 2];
    b1[l] = (const float*)d_in[i0 + 3];
    g[l] = (const float*)d_in[i0 + 4];
    bt[l] = (const float*)d_in[i0 + 5];
    W2[l] = (const float*)d_in[i0 + 6];
    b2[l] = (const float*)d_in[i0 + 7];
  }
  const float* Wf1 = (const float*)d_in[29];
  const float* bf1 = (const float*)d_in[30];
  const float* Wf2 = (const float*)d_in[31];
  const float* bf2 = (const float*)d_in[32];
  float* out = (float*)d_out;

  const size_t NH = (size_t)N_NODES * HID;
  u16* xb = (u16*)d_ws;                  // [N,128] bf16 layer output
  u16* abuf = xb + NH;                   // [N,128] bf16 aggregation
  u16* hbuf = abuf + NH;                 // [N,128] bf16 hidden (pre-BN)
  float* stat0 = (float*)(hbuf + NH);    // 3 x [256]
  float* stat1 = stat0 + 256;
  float* stat2 = stat1 + 256;
  float* pooled = stat2 + 256;           // [64,128]
  u16* wt = (u16*)(pooled + NB * HID);   // 5 x [128,128] bf16 (contiguous)
  int* bcur = (int*)(wt + 5 * HID * HID);  // [160]
  int* offs = bcur + 160;                // [40002]
  u64* elc = (u64*)(offs + 40002);       // [CB*BCAP] bucketed records
  uint2* elpk = (uint2*)(elc + (size_t)CB * BCAP);  // [E] dst-sorted records
  float* stats[3] = {stat0, stat1, stat2};
  // wt order: [0]=W2t l0, [1]=W1t l1, [2]=W2t l1, [3]=W1t l2, [4]=W2t l2

  // ---------------- W transposes + init (one launch, runs first) ----------
  hipLaunchKernelGGL(wconv5_init, dim3(5 * HID), dim3(HID), 0, stream, W2[0],
                     W1[1], W2[1], W1[2], W2[2], wt, bcur, stat0, pooled);

  // ---------------- CSR build: fixed-capacity radix partition --------------
  hipLaunchKernelGGL(partition1, dim3(P1B), dim3(256), 0, stream, ei, ea, bcur,
                     elc);
  hipLaunchKernelGGL(partition2, dim3(CB), dim3(256), 0, stream, elc, bcur,
                     elpk, offs);

  const int GMB = 313;  // gemm_mfma grid: 1252 waves, 2 tiles/wave (optimum)
  const size_t WT = (size_t)HID * HID;

  // ---------------- Layer 0 (d = 16): fused aggregate + K=16 GEMM ----------
  hipLaunchKernelGGL(agg_gemm16, dim3(N_NODES / 32), dim3(256), 0, stream,
                     x_in, offs, elpk, We[0], be[0], W1[0], b1[0], hbuf,
                     stat0);
  hipLaunchKernelGGL((gemm_mfma<true, false, true>), dim3(GMB), dim3(256), 0,
                     stream, hbuf, wt, b2[0], stat0, g[0], bt[0], xb, nullptr);

  // ---------------- Layers 1, 2 (d = 128) ----------------
  for (int l = 1; l < 3; l++) {
    hipLaunchKernelGGL(aggregate128_bf16, dim3(N_NODES), dim3(64), 0, stream,
                       xb, offs, elpk, We[l], be[l], abuf);
    hipLaunchKernelGGL((gemm_mfma<false, true, false>), dim3(GMB), dim3(256),
                       0, stream, abuf, wt + (2 * l - 1) * WT, b1[l], nullptr,
                       nullptr, nullptr, hbuf, stats[l]);
    hipLaunchKernelGGL((gemm_mfma<true, false, true>), dim3(GMB), dim3(256), 0,
                       stream, hbuf, wt + (2 * l) * WT, b2[l], stats[l], g[l],
                       bt[l], xb, nullptr);
  }

  // ---------------- Pool + final MLP ----------------
  hipLaunchKernelGGL(pool_kernel, dim3(POOL_NBLK), dim3(64), 0, stream, xb,
                     batch, pooled);
  hipLaunchKernelGGL(final_mlp, dim3(NB), dim3(128), 0, stream, pooled, Wf1,
                     bf1, Wf2, bf2, out);
}